// Round 1
// baseline (836.455 us; speedup 1.0000x reference)
//
#include <hip/hip_runtime.h>
#include <hip/hip_bf16.h>

#define Bn 16
#define Cn 2048
#define Qn 128
#define En 200
#define Fn 800
#define On 128

// ---------------- k_yq: yq[b,q,e] = xq*w3 + w1 ; s_q[b,q] = dot(xq, w2) ----
__global__ void k_yq(const float* __restrict__ xq, const float* __restrict__ wsim,
                     float* __restrict__ yq, float* __restrict__ s_q) {
    int wid = (blockIdx.x * blockDim.x + threadIdx.x) >> 6;  // one wave per (b,q) row
    int lane = threadIdx.x & 63;
    if (wid >= Bn * Qn) return;
    const float* xrow = xq + wid * En;
    float* yrow = yq + wid * En;
    float s = 0.f;
    for (int e = lane; e < En; e += 64) {
        float x = xrow[e];
        yrow[e] = x * wsim[400 + e] + wsim[e];
        s += x * wsim[200 + e];
    }
    for (int i = 32; i; i >>= 1) s += __shfl_xor(s, i, 64);
    if (lane == 0) s_q[wid] = s;
}

// ---------------- k_wpt: transpose w_proj [128][800] -> wpT [800][128] -----
__global__ void k_wpt(const float* __restrict__ wp, float* __restrict__ wpT) {
    int idx = blockIdx.x * 256 + threadIdx.x;  // f*128 + o
    if (idx >= Fn * On) return;
    int f = idx >> 7, o = idx & 127;
    wpT[idx] = wp[o * Fn + f];
}

// ---------------- k_scores: scores[b,c,q] = xc[c,:] . yq[q,:] + s_q[q] -----
__global__ __launch_bounds__(256) void k_scores(const float* __restrict__ xc,
                                                const float* __restrict__ yq,
                                                const float* __restrict__ s_q,
                                                float* __restrict__ scores) {
    int b = blockIdx.y;
    int c0 = blockIdx.x * 16;
    int tid = threadIdx.x;
    int q = tid & 127, ch = tid >> 7;  // ch in {0,1}: c-rows ch*8..ch*8+7
    __shared__ float yql[128 * 51];    // [q][e], pitch 51 (odd -> conflict-free)
    __shared__ float xcl[16 * 50];
    float acc[8];
#pragma unroll
    for (int i = 0; i < 8; i++) acc[i] = 0.f;
    const float* yqb = yq + b * Qn * En;
    const float* xcb = xc + (size_t)(b * Cn + c0) * En;
    for (int chunk = 0; chunk < 4; chunk++) {
        __syncthreads();
        int e0 = chunk * 50;
        for (int i = tid; i < 128 * 50; i += 256) {
            int qq = i / 50, ee = i % 50;
            yql[qq * 51 + ee] = yqb[qq * En + e0 + ee];
        }
        for (int i = tid; i < 16 * 50; i += 256) {
            int cc = i / 50, ee = i % 50;
            xcl[cc * 50 + ee] = xcb[cc * En + e0 + ee];
        }
        __syncthreads();
        for (int e = 0; e < 50; e++) {
            float yv = yql[q * 51 + e];
#pragma unroll
            for (int c8 = 0; c8 < 8; c8++) acc[c8] += xcl[(ch * 8 + c8) * 50 + e] * yv;
        }
    }
    float sq = s_q[b * Qn + q];
#pragma unroll
    for (int c8 = 0; c8 < 8; c8++)
        scores[(size_t)(b * Cn + c0 + ch * 8 + c8) * Qn + q] = acc[c8] + sq;
}

// ---------------- k_rowstat: per (b,c)-row max & 1/sum(exp) over q ---------
__global__ void k_rowstat(const float* __restrict__ scores,
                          float* __restrict__ rowM, float* __restrict__ rowSi) {
    int wid = (blockIdx.x * blockDim.x + threadIdx.x) >> 6;  // one wave per row
    int lane = threadIdx.x & 63;
    if (wid >= Bn * Cn) return;
    const float* row = scores + (size_t)wid * Qn;
    float x0 = row[lane], x1 = row[lane + 64];
    float m = fmaxf(x0, x1);
    for (int i = 32; i; i >>= 1) m = fmaxf(m, __shfl_xor(m, i, 64));
    float s = __expf(x0 - m) + __expf(x1 - m);
    for (int i = 32; i; i >>= 1) s += __shfl_xor(s, i, 64);
    if (lane == 0) { rowM[wid] = m; rowSi[wid] = 1.f / s; }
}

// ---------------- k_colpart: online (max,sumexp) over 128-row c-chunks -----
__global__ void k_colpart(const float* __restrict__ scores,
                          float* __restrict__ cpM, float* __restrict__ cpS) {
    int b = blockIdx.y, cch = blockIdx.x;  // 16 x 16
    int q = threadIdx.x;                    // 128
    const float* base = scores + (size_t)(b * Cn + cch * 128) * Qn + q;
    float m = -1e30f, s = 0.f;
    for (int c = 0; c < 128; c++) {
        float x = base[(size_t)c * Qn];
        float nm = fmaxf(m, x);
        s = s * __expf(m - nm) + __expf(x - nm);
        m = nm;
    }
    cpM[(b * 16 + cch) * 128 + q] = m;
    cpS[(b * 16 + cch) * 128 + q] = s;
}

// ---------------- k_colcomb: combine 16 partials -> colM, colS -------------
__global__ void k_colcomb(const float* __restrict__ cpM, const float* __restrict__ cpS,
                          float* __restrict__ colM, float* __restrict__ colS) {
    int b = blockIdx.x, q = threadIdx.x;
    float m = -1e30f;
    for (int k = 0; k < 16; k++) m = fmaxf(m, cpM[(b * 16 + k) * 128 + q]);
    float s = 0.f;
    for (int k = 0; k < 16; k++) s += cpS[(b * 16 + k) * 128 + q] * __expf(cpM[(b * 16 + k) * 128 + q] - m);
    colM[b * 128 + q] = m;
    colS[b * 128 + q] = s;
}

// ---------------- k_a: a[b,q,e] = sum_c S2[b,c,q] * xc[b,c,e] (partials) ---
__global__ __launch_bounds__(256) void k_a(const float* __restrict__ scores,
                                           const float* __restrict__ xc,
                                           const float* __restrict__ colM,
                                           const float* __restrict__ colS,
                                           float* __restrict__ aPart) {
    int cch = blockIdx.x, qt = blockIdx.y, b = blockIdx.z;  // 4,4,16
    int q0 = qt * 32, c0 = cch * 512;
    int tid = threadIdx.x;
    __shared__ float s2t[32 * 32];
    __shared__ float xct[32 * En];
    __shared__ float cm[32], csi[32];
    if (tid < 32) {
        cm[tid] = colM[b * Qn + q0 + tid];
        csi[tid] = 1.f / colS[b * Qn + q0 + tid];
    }
    float acc[32];
#pragma unroll
    for (int j = 0; j < 32; j++) acc[j] = 0.f;
    __syncthreads();
    for (int chunk = 0; chunk < 16; chunk++) {
        int cc0 = c0 + chunk * 32;
        __syncthreads();
        for (int i = tid; i < 1024; i += 256) {
            int ci = i >> 5, j = i & 31;
            float x = scores[(size_t)(b * Cn + cc0 + ci) * Qn + q0 + j];
            s2t[i] = __expf(x - cm[j]) * csi[j];
        }
        for (int i = tid; i < 32 * En; i += 256)
            xct[i] = xc[(size_t)(b * Cn + cc0) * En + i];
        __syncthreads();
        if (tid < En) {
            int e = tid;
            for (int ci = 0; ci < 32; ci++) {
                float xv = xct[ci * En + e];
#pragma unroll
                for (int j = 0; j < 32; j++) acc[j] += s2t[ci * 32 + j] * xv;
            }
        }
    }
    if (tid < En) {
#pragma unroll
        for (int j = 0; j < 32; j++)
            aPart[((size_t)(b * 4 + cch) * Qn + q0 + j) * En + tid] = acc[j];
    }
}

// ---------------- k_acomb: reduce 4 c-chunk partials -----------------------
__global__ void k_acomb(const float* __restrict__ aPart, float* __restrict__ a) {
    int i = blockIdx.x * 256 + threadIdx.x;
    if (i >= Bn * Qn * En) return;
    int b = i / (Qn * En), r = i % (Qn * En);
    float s = 0.f;
    for (int k = 0; k < 4; k++) s += aPart[(size_t)(b * 4 + k) * Qn * En + r];
    a[i] = s;
}

// ---------------- k_big: fused c2q/q2c + feats + projection ----------------
// block = (b, c-tile of 16 rows), 256 threads, 149KB LDS
__global__ __launch_bounds__(256) void k_big(const float* __restrict__ scores,
                                             const float* __restrict__ rowM,
                                             const float* __restrict__ rowSi,
                                             const float* __restrict__ xc,
                                             const float* __restrict__ xq,
                                             const float* __restrict__ a,
                                             const float* __restrict__ wpT,
                                             const float* __restrict__ bp,
                                             float* __restrict__ out) {
    int b = blockIdx.y;
    int c0 = blockIdx.x * 16;
    int tid = threadIdx.x;
    __shared__ float lds[37248];
    float* xqa = lds;           // 25600: xq_half [128][100] @0, a_half @12800 (reused as feat[16][800])
    float* s1t = lds + 25600;   // 2048: S1 tile [16][128]
    float* c2q = lds + 27648;   // 3200
    float* q2c = lds + 30848;   // 3200
    float* xcl = lds + 34048;   // 3200
    // stage S1 tile (recompute from scores + row stats) and xc tile
    for (int i = tid; i < 2048; i += 256) {
        int ci = i >> 7;
        s1t[i] = __expf(scores[(size_t)(b * Cn + c0) * Qn + i] - rowM[b * Cn + c0 + ci]) * rowSi[b * Cn + c0 + ci];
    }
    for (int i = tid; i < 3200; i += 256)
        xcl[i] = xc[(size_t)(b * Cn + c0) * En + i];
    int e1 = tid % 100, cs = tid / 100;  // active threads: tid<200 -> cs in {0,1}
    for (int h = 0; h < 2; h++) {
        __syncthreads();
        for (int i = tid; i < 12800; i += 256) {
            int qq = i / 100, ee = i % 100;
            xqa[i] = xq[(size_t)(b * Qn + qq) * En + h * 100 + ee];
        }
        for (int i = tid; i < 12800; i += 256) {
            int qq = i / 100, ee = i % 100;
            xqa[12800 + i] = a[(size_t)(b * Qn + qq) * En + h * 100 + ee];
        }
        __syncthreads();
        if (tid < 200) {
            float acc1[8], acc2[8];
#pragma unroll
            for (int i = 0; i < 8; i++) { acc1[i] = 0.f; acc2[i] = 0.f; }
            for (int qq = 0; qq < 128; qq++) {
                float xv = xqa[qq * 100 + e1];
                float av = xqa[12800 + qq * 100 + e1];
#pragma unroll
                for (int c8 = 0; c8 < 8; c8++) {
                    float s = s1t[(cs * 8 + c8) * 128 + qq];
                    acc1[c8] += s * xv;
                    acc2[c8] += s * av;
                }
            }
#pragma unroll
            for (int c8 = 0; c8 < 8; c8++) {
                c2q[(cs * 8 + c8) * En + h * 100 + e1] = acc1[c8];
                q2c[(cs * 8 + c8) * En + h * 100 + e1] = acc2[c8];
            }
        }
    }
    __syncthreads();
    // build feats[16][800] into xqa region
    for (int i = tid; i < 12800; i += 256) {
        int c = i / Fn, f = i % Fn;
        int sel = f / En, e = f % En;
        float x = xcl[c * En + e];
        float v;
        if (sel == 0) v = x;
        else if (sel == 1) v = c2q[c * En + e];
        else if (sel == 2) v = x * c2q[c * En + e];
        else v = x * q2c[c * En + e];
        xqa[i] = v;
    }
    __syncthreads();
    // projection: out[c, o] = feats[c,:] . wpT[:,o] + bp[o]
    int o = tid & 127, cg = tid >> 7;
    float acc[8];
    float bpv = bp[o];
#pragma unroll
    for (int i = 0; i < 8; i++) acc[i] = bpv;
    for (int f = 0; f < Fn; f++) {
        float w = wpT[f * On + o];
#pragma unroll
        for (int c8 = 0; c8 < 8; c8++) acc[c8] += xqa[(cg * 8 + c8) * Fn + f] * w;
    }
#pragma unroll
    for (int c8 = 0; c8 < 8; c8++)
        out[(size_t)(b * Cn + c0 + cg * 8 + c8) * On + o] = acc[c8];
}

extern "C" void kernel_launch(void* const* d_in, const int* in_sizes, int n_in,
                              void* d_out, int out_size, void* d_ws, size_t ws_size,
                              hipStream_t stream) {
    const float* xc = (const float*)d_in[0];
    const float* xq = (const float*)d_in[1];
    const float* wsim = (const float*)d_in[2];
    const float* wp = (const float*)d_in[3];
    const float* bp = (const float*)d_in[4];
    float* out = (float*)d_out;
    float* ws = (float*)d_ws;

    float* yq    = ws;                 // 409600
    float* s_q   = ws + 409600;        // 2048
    float* sc    = ws + 411648;        // 4194304
    float* rowM  = ws + 4605952;       // 32768
    float* rowSi = ws + 4638720;       // 32768
    float* cpM   = ws + 4671488;       // 32768
    float* cpS   = ws + 4704256;       // 32768
    float* colM  = ws + 4737024;       // 2048
    float* colS  = ws + 4739072;       // 2048
    float* aPart = ws + 4741120;       // 1638400
    float* a     = ws + 6379520;       // 409600
    float* wpT   = ws + 6789120;       // 102400  (total 6891520 floats = 27.6MB)

    k_yq<<<512, 256, 0, stream>>>(xq, wsim, yq, s_q);
    k_wpt<<<400, 256, 0, stream>>>(wp, wpT);
    k_scores<<<dim3(128, 16), 256, 0, stream>>>(xc, yq, s_q, sc);
    k_rowstat<<<8192, 256, 0, stream>>>(sc, rowM, rowSi);
    k_colpart<<<dim3(16, 16), 128, 0, stream>>>(sc, cpM, cpS);
    k_colcomb<<<16, 128, 0, stream>>>(cpM, cpS, colM, colS);
    k_a<<<dim3(4, 4, 16), 256, 0, stream>>>(sc, xc, colM, colS, aPart);
    k_acomb<<<1600, 256, 0, stream>>>(aPart, a);
    k_big<<<dim3(128, 16), 256, 0, stream>>>(sc, rowM, rowSi, xc, xq, a, wpT, bp, out);
}

// Round 2
// 303.069 us; speedup vs baseline: 2.7600x; 2.7600x over previous
//
#include <hip/hip_runtime.h>
#include <hip/hip_bf16.h>

#define Bn 16
#define Cn 2048
#define Qn 128
#define En 200
#define Fn 800
#define On 128

typedef float f32x4 __attribute__((ext_vector_type(4)));
typedef __bf16 bf16x8 __attribute__((ext_vector_type(8)));

__device__ __forceinline__ unsigned short f2bf(float f) {
    union { float f; unsigned u; } v; v.f = f;
    unsigned r = v.u + 0x7FFF + ((v.u >> 16) & 1);
    return (unsigned short)(r >> 16);
}
__device__ __forceinline__ float bf2f(unsigned short h) {
    union { unsigned u; float f; } v; v.u = (unsigned)h << 16;
    return v.f;
}

// ---------------- k_yq: yq[b,q,e] = xq*w3 + w1 ; s_q[b,q] = dot(xq, w2) ----
__global__ void k_yq(const float* __restrict__ xq, const float* __restrict__ wsim,
                     float* __restrict__ yq, float* __restrict__ s_q) {
    int wid = (blockIdx.x * blockDim.x + threadIdx.x) >> 6;
    int lane = threadIdx.x & 63;
    if (wid >= Bn * Qn) return;
    const float* xrow = xq + wid * En;
    float* yrow = yq + wid * En;
    float s = 0.f;
    for (int e = lane; e < En; e += 64) {
        float x = xrow[e];
        yrow[e] = x * wsim[400 + e] + wsim[e];
        s += x * wsim[200 + e];
    }
    for (int i = 32; i; i >>= 1) s += __shfl_xor(s, i, 64);
    if (lane == 0) s_q[wid] = s;
}

// ---------------- k_scores: scores[b,c,q] = xc[c,:] . yq[q,:] + s_q[q] -----
__global__ __launch_bounds__(256) void k_scores(const float* __restrict__ xc,
                                                const float* __restrict__ yq,
                                                const float* __restrict__ s_q,
                                                float* __restrict__ scores) {
    int b = blockIdx.y;
    int c0 = blockIdx.x * 16;
    int tid = threadIdx.x;
    int q = tid & 127, ch = tid >> 7;
    __shared__ float yql[128 * 51];
    __shared__ float xcl[16 * 50];
    float acc[8];
#pragma unroll
    for (int i = 0; i < 8; i++) acc[i] = 0.f;
    const float* yqb = yq + b * Qn * En;
    const float* xcb = xc + (size_t)(b * Cn + c0) * En;
    for (int chunk = 0; chunk < 4; chunk++) {
        __syncthreads();
        int e0 = chunk * 50;
        for (int i = tid; i < 128 * 50; i += 256) {
            int qq = i / 50, ee = i % 50;
            yql[qq * 51 + ee] = yqb[qq * En + e0 + ee];
        }
        for (int i = tid; i < 16 * 50; i += 256) {
            int cc = i / 50, ee = i % 50;
            xcl[cc * 50 + ee] = xcb[cc * En + e0 + ee];
        }
        __syncthreads();
        for (int e = 0; e < 50; e++) {
            float yv = yql[q * 51 + e];
#pragma unroll
            for (int c8 = 0; c8 < 8; c8++) acc[c8] += xcl[(ch * 8 + c8) * 50 + e] * yv;
        }
    }
    float sq = s_q[b * Qn + q];
#pragma unroll
    for (int c8 = 0; c8 < 8; c8++)
        scores[(size_t)(b * Cn + c0 + ch * 8 + c8) * Qn + q] = acc[c8] + sq;
}

// ---------------- k_rowstat ------------------------------------------------
__global__ void k_rowstat(const float* __restrict__ scores,
                          float* __restrict__ rowM, float* __restrict__ rowSi) {
    int wid = (blockIdx.x * blockDim.x + threadIdx.x) >> 6;
    int lane = threadIdx.x & 63;
    if (wid >= Bn * Cn) return;
    const float* row = scores + (size_t)wid * Qn;
    float x0 = row[lane], x1 = row[lane + 64];
    float m = fmaxf(x0, x1);
    for (int i = 32; i; i >>= 1) m = fmaxf(m, __shfl_xor(m, i, 64));
    float s = __expf(x0 - m) + __expf(x1 - m);
    for (int i = 32; i; i >>= 1) s += __shfl_xor(s, i, 64);
    if (lane == 0) { rowM[wid] = m; rowSi[wid] = 1.f / s; }
}

// ---------------- k_colpart ------------------------------------------------
__global__ void k_colpart(const float* __restrict__ scores,
                          float* __restrict__ cpM, float* __restrict__ cpS) {
    int b = blockIdx.y, cch = blockIdx.x;
    int q = threadIdx.x;
    const float* base = scores + (size_t)(b * Cn + cch * 128) * Qn + q;
    float m = -1e30f, s = 0.f;
    for (int c = 0; c < 128; c++) {
        float x = base[(size_t)c * Qn];
        float nm = fmaxf(m, x);
        s = s * __expf(m - nm) + __expf(x - nm);
        m = nm;
    }
    cpM[(b * 16 + cch) * 128 + q] = m;
    cpS[(b * 16 + cch) * 128 + q] = s;
}

// ---------------- k_colcomb ------------------------------------------------
__global__ void k_colcomb(const float* __restrict__ cpM, const float* __restrict__ cpS,
                          float* __restrict__ colM, float* __restrict__ colS) {
    int b = blockIdx.x, q = threadIdx.x;
    float m = -1e30f;
    for (int k = 0; k < 16; k++) m = fmaxf(m, cpM[(b * 16 + k) * 128 + q]);
    float s = 0.f;
    for (int k = 0; k < 16; k++) s += cpS[(b * 16 + k) * 128 + q] * __expf(cpM[(b * 16 + k) * 128 + q] - m);
    colM[b * 128 + q] = m;
    colS[b * 128 + q] = s;
}

// ---------------- k_a: a[b,q,e] = sum_c S2[b,c,q] * xc[b,c,e] (partials) ---
__global__ __launch_bounds__(256) void k_a(const float* __restrict__ scores,
                                           const float* __restrict__ xc,
                                           const float* __restrict__ colM,
                                           const float* __restrict__ colS,
                                           float* __restrict__ aPart) {
    int cch = blockIdx.x, qt = blockIdx.y, b = blockIdx.z;
    int q0 = qt * 32, c0 = cch * 512;
    int tid = threadIdx.x;
    __shared__ float s2t[32 * 32];
    __shared__ float xct[32 * En];
    __shared__ float cm[32], csi[32];
    if (tid < 32) {
        cm[tid] = colM[b * Qn + q0 + tid];
        csi[tid] = 1.f / colS[b * Qn + q0 + tid];
    }
    float acc[32];
#pragma unroll
    for (int j = 0; j < 32; j++) acc[j] = 0.f;
    __syncthreads();
    for (int chunk = 0; chunk < 16; chunk++) {
        int cc0 = c0 + chunk * 32;
        __syncthreads();
        for (int i = tid; i < 1024; i += 256) {
            int ci = i >> 5, j = i & 31;
            float x = scores[(size_t)(b * Cn + cc0 + ci) * Qn + q0 + j];
            s2t[i] = __expf(x - cm[j]) * csi[j];
        }
        for (int i = tid; i < 32 * En; i += 256)
            xct[i] = xc[(size_t)(b * Cn + cc0) * En + i];
        __syncthreads();
        if (tid < En) {
            int e = tid;
            for (int ci = 0; ci < 32; ci++) {
                float xv = xct[ci * En + e];
#pragma unroll
                for (int j = 0; j < 32; j++) acc[j] += s2t[ci * 32 + j] * xv;
            }
        }
    }
    if (tid < En) {
#pragma unroll
        for (int j = 0; j < 32; j++)
            aPart[((size_t)(b * 4 + cch) * Qn + q0 + j) * En + tid] = acc[j];
    }
}

// ---------------- k_acomb --------------------------------------------------
__global__ void k_acomb(const float* __restrict__ aPart, float* __restrict__ a) {
    int i = blockIdx.x * 256 + threadIdx.x;
    if (i >= Bn * Qn * En) return;
    int b = i / (Qn * En), r = i % (Qn * En);
    float s = 0.f;
    for (int k = 0; k < 4; k++) s += aPart[(size_t)(b * 4 + k) * Qn * En + r];
    a[i] = s;
}

// ---------------- k_prep_s1: S1 bf16 [b][c][q] -----------------------------
__global__ void k_prep_s1(const float* __restrict__ sc, const float* __restrict__ rowM,
                          const float* __restrict__ rowSi, unsigned short* __restrict__ s1) {
    int gid = blockIdx.x * 256 + threadIdx.x;   // handles 4 consecutive q
    int base = gid * 4;
    int row = base >> 7;                         // (b*2048 + c)
    float m = rowM[row], si = rowSi[row];
    float4 v = *(const float4*)(sc + base);
    ushort4 o;
    o.x = f2bf(__expf(v.x - m) * si);
    o.y = f2bf(__expf(v.y - m) * si);
    o.z = f2bf(__expf(v.z - m) * si);
    o.w = f2bf(__expf(v.w - m) * si);
    *(ushort4*)(s1 + base) = o;
}

// ---------------- k_prep_xqa: xqaT bf16 [b][400][128] ----------------------
__global__ void k_prep_xqa(const float* __restrict__ xq, const float* __restrict__ a,
                           unsigned short* __restrict__ xqaT) {
    int gid = blockIdx.x * 256 + threadIdx.x;
    if (gid >= Bn * 400 * 128) return;
    int b = gid / (400 * 128), r = gid % (400 * 128);
    int ep = r >> 7, q = r & 127;
    float v = (ep < En) ? xq[((size_t)(b * Qn + q)) * En + ep]
                        : a[((size_t)(b * Qn + q)) * En + (ep - En)];
    xqaT[gid] = f2bf(v);
}

// ---------------- k_prep_wp: w_proj bf16 [128][800] ------------------------
__global__ void k_prep_wp(const float* __restrict__ wp, unsigned short* __restrict__ wpb) {
    int gid = blockIdx.x * 256 + threadIdx.x;
    int base = gid * 4;
    if (base >= On * Fn) return;
    float4 v = *(const float4*)(wp + base);
    ushort4 o;
    o.x = f2bf(v.x); o.y = f2bf(v.y); o.z = f2bf(v.z); o.w = f2bf(v.w);
    *(ushort4*)(wpb + base) = o;
}

// ---------------- k_cq: MFMA GEMM  [c2q|q2c] = S1 @ xqaT^T -----------------
// per b: M=2048 (c), N=400 (e'), K=128 (q). Block: 64x80 tile, 4 waves.
__global__ __launch_bounds__(256) void k_cq(const unsigned short* __restrict__ s1,
                                            const unsigned short* __restrict__ xqaT,
                                            unsigned short* __restrict__ cq) {
    int b = blockIdx.z;
    int c0 = blockIdx.x * 64;
    int n0 = blockIdx.y * 80;
    int w = threadIdx.x >> 6, lane = threadIdx.x & 63;
    int lrow = lane & 15, kg = lane >> 4;
    const unsigned short* Abase = s1 + ((size_t)(b * Cn + c0 + w * 16 + lrow)) * 128 + kg * 8;
    const unsigned short* Bbase = xqaT + ((size_t)(b * 400 + n0 + lrow)) * 128 + kg * 8;
    f32x4 acc[5] = {};
#pragma unroll
    for (int kc = 0; kc < 4; ++kc) {
        bf16x8 af = *(const bf16x8*)(Abase + kc * 32);
#pragma unroll
        for (int j = 0; j < 5; ++j) {
            bf16x8 bfr = *(const bf16x8*)(Bbase + (size_t)j * 16 * 128 + kc * 32);
            acc[j] = __builtin_amdgcn_mfma_f32_16x16x32_bf16(af, bfr, acc[j], 0, 0, 0);
        }
    }
    int drow = c0 + w * 16 + kg * 4;
#pragma unroll
    for (int j = 0; j < 5; ++j) {
#pragma unroll
        for (int r = 0; r < 4; ++r) {
            cq[((size_t)(b * Cn + drow + r)) * 400 + n0 + j * 16 + lrow] = f2bf(acc[j][r]);
        }
    }
}

// ---------------- k_out: feats build (LDS, bf16) + MFMA projection ---------
// per (b, 16-c tile): out[16][128] = feats[16][800] @ wp^T, K-chunks of 32.
__global__ __launch_bounds__(256) void k_out(const float* __restrict__ xc,
                                             const unsigned short* __restrict__ cq,
                                             const unsigned short* __restrict__ wpb,
                                             const float* __restrict__ bp,
                                             float* __restrict__ out) {
    int b = blockIdx.y;
    int c0 = blockIdx.x * 16;
    int tid = threadIdx.x;
    __shared__ unsigned short feats[16 * 808];   // pad 800->808: 2-way max conflicts
    const float* xcb = xc + ((size_t)(b * Cn + c0)) * En;
    const unsigned short* cqb = cq + ((size_t)(b * Cn + c0)) * 400;
    for (int i = tid; i < 16 * 800; i += 256) {
        int c = i / 800, f = i % 800;
        int sel = f / 200, e = f % 200;
        float v;
        if (sel == 0)      v = xcb[c * En + e];
        else if (sel == 1) v = bf2f(cqb[c * 400 + e]);
        else if (sel == 2) v = xcb[c * En + e] * bf2f(cqb[c * 400 + e]);
        else               v = xcb[c * En + e] * bf2f(cqb[c * 400 + 200 + e]);
        feats[c * 808 + f] = f2bf(v);
    }
    __syncthreads();
    int w = tid >> 6, lane = tid & 63;
    int lrow = lane & 15, kg = lane >> 4;
    f32x4 acc[2] = {};
    const unsigned short* Bbase = wpb + ((size_t)(w * 32 + lrow)) * Fn + kg * 8;
    const unsigned short* Af = feats + lrow * 808 + kg * 8;
#pragma unroll 5
    for (int kc = 0; kc < 25; ++kc) {
        bf16x8 af = *(const bf16x8*)(Af + kc * 32);
#pragma unroll
        for (int j = 0; j < 2; ++j) {
            bf16x8 bfr = *(const bf16x8*)(Bbase + (size_t)j * 16 * Fn + kc * 32);
            acc[j] = __builtin_amdgcn_mfma_f32_16x16x32_bf16(af, bfr, acc[j], 0, 0, 0);
        }
    }
    int drow0 = kg * 4;
#pragma unroll
    for (int j = 0; j < 2; ++j) {
        int col = w * 32 + j * 16 + lrow;
        float bpv = bp[col];
#pragma unroll
        for (int r = 0; r < 4; ++r) {
            out[((size_t)(b * Cn + c0 + drow0 + r)) * On + col] = acc[j][r] + bpv;
        }
    }
}

extern "C" void kernel_launch(void* const* d_in, const int* in_sizes, int n_in,
                              void* d_out, int out_size, void* d_ws, size_t ws_size,
                              hipStream_t stream) {
    const float* xc = (const float*)d_in[0];
    const float* xq = (const float*)d_in[1];
    const float* wsim = (const float*)d_in[2];
    const float* wp = (const float*)d_in[3];
    const float* bp = (const float*)d_in[4];
    float* out = (float*)d_out;
    float* ws = (float*)d_ws;

    // Region A (dead before k_cq; aliased by cq_bf):
    float* sc    = ws;                  // 4,194,304 f
    float* aPart = ws + 4194304;        // 1,638,400 f
    float* yq    = ws + 5832704;        //   409,600 f
    float* cpM   = ws + 6242304;        //    32,768 f
    float* cpS   = ws + 6275072;        //    32,768 f
    unsigned short* cq_bf = (unsigned short*)ws;  // 13,107,200 bf16 = 6,553,600 f (aliases region A)
    // Persistent region (>= 6,553,600 f):
    float* s_q   = ws + 6553600;        //     2,048 f
    float* rowM  = ws + 6555648;        //    32,768 f
    float* rowSi = ws + 6588416;        //    32,768 f
    float* colM  = ws + 6621184;        //     2,048 f
    float* colS  = ws + 6623232;        //     2,048 f
    float* a     = ws + 6625280;        //   409,600 f
    unsigned short* s1_bf   = (unsigned short*)(ws + 7034880);  // 4,194,304 bf16
    unsigned short* xqaT_bf = (unsigned short*)(ws + 9132032);  //   819,200 bf16
    unsigned short* wp_bf   = (unsigned short*)(ws + 9541632);  //   102,400 bf16
    // total: 9,592,832 floats = 38.4 MB

    k_yq<<<512, 256, 0, stream>>>(xq, wsim, yq, s_q);
    k_prep_wp<<<100, 256, 0, stream>>>(wp, wp_bf);
    k_scores<<<dim3(128, 16), 256, 0, stream>>>(xc, yq, s_q, sc);
    k_rowstat<<<8192, 256, 0, stream>>>(sc, rowM, rowSi);
    k_colpart<<<dim3(16, 16), 128, 0, stream>>>(sc, cpM, cpS);
    k_colcomb<<<16, 128, 0, stream>>>(cpM, cpS, colM, colS);
    k_a<<<dim3(4, 4, 16), 256, 0, stream>>>(sc, xc, colM, colS, aPart);
    k_acomb<<<1600, 256, 0, stream>>>(aPart, a);
    k_prep_s1<<<4096, 256, 0, stream>>>(sc, rowM, rowSi, s1_bf);
    k_prep_xqa<<<3200, 256, 0, stream>>>(xq, a, xqaT_bf);
    // Region A is dead from here; cq_bf may alias it.
    k_cq<<<dim3(32, 5, 16), 256, 0, stream>>>(s1_bf, xqaT_bf, cq_bf);
    k_out<<<dim3(128, 16), 256, 0, stream>>>(xc, cq_bf, wp_bf, bp, out);
}

// Round 3
// 181.489 us; speedup vs baseline: 4.6089x; 1.6699x over previous
//
#include <hip/hip_runtime.h>
#include <hip/hip_bf16.h>

#define Bn 16
#define Cn 2048
#define Qn 128
#define En 200
#define Fn 800
#define On 128
#define EP 208  // padded e-rows for xcT

typedef float f32x4 __attribute__((ext_vector_type(4)));
typedef __bf16 bf16x8 __attribute__((ext_vector_type(8)));

__device__ __forceinline__ unsigned short f2bf(float f) {
    union { float f; unsigned u; } v; v.f = f;
    unsigned r = v.u + 0x7FFF + ((v.u >> 16) & 1);
    return (unsigned short)(r >> 16);
}
__device__ __forceinline__ float bf2f(unsigned short h) {
    union { unsigned u; float f; } v; v.u = (unsigned)h << 16;
    return v.f;
}

// ---- k_yq: yq_bf[b,q,e] = bf16(xq*w3 + w1); s_q[b,q] = dot(xq, w2) --------
__global__ void k_yq(const float* __restrict__ xq, const float* __restrict__ wsim,
                     unsigned short* __restrict__ yqb, float* __restrict__ s_q) {
    int wid = (blockIdx.x * blockDim.x + threadIdx.x) >> 6;
    int lane = threadIdx.x & 63;
    if (wid >= Bn * Qn) return;
    const float* xrow = xq + (size_t)wid * En;
    float s = 0.f;
    for (int e = lane; e < En; e += 64) {
        float x = xrow[e];
        yqb[(size_t)wid * En + e] = f2bf(x * wsim[400 + e] + wsim[e]);
        s += x * wsim[200 + e];
    }
    for (int i = 32; i; i >>= 1) s += __shfl_xor(s, i, 64);
    if (lane == 0) s_q[wid] = s;
}

// ---- k_cast_xc: xc fp32 -> bf16 (same layout) -----------------------------
__global__ void k_cast_xc(const float* __restrict__ xc, unsigned short* __restrict__ xcb) {
    int gid = blockIdx.x * 256 + threadIdx.x;
    int base = gid * 4;
    if (base >= Bn * Cn * En) return;
    float4 v = *(const float4*)(xc + base);
    ushort4 o;
    o.x = f2bf(v.x); o.y = f2bf(v.y); o.z = f2bf(v.z); o.w = f2bf(v.w);
    *(ushort4*)(xcb + base) = o;
}

// ---- k_prep_wp: w_proj -> bf16 [128][800] ---------------------------------
__global__ void k_prep_wp(const float* __restrict__ wp, unsigned short* __restrict__ wpb) {
    int gid = blockIdx.x * 256 + threadIdx.x;
    int base = gid * 4;
    if (base >= On * Fn) return;
    float4 v = *(const float4*)(wp + base);
    ushort4 o;
    o.x = f2bf(v.x); o.y = f2bf(v.y); o.z = f2bf(v.z); o.w = f2bf(v.w);
    *(ushort4*)(wpb + base) = o;
}

// ---- k_scores_mfma: scores = xc_bf @ yq_bf^T + s_q; fused row softmax -----
// grid (32 ctiles, 16 b), 4 waves; wave w: rows c0+w*16..+16, all 128 q.
__global__ __launch_bounds__(256) void k_scores_mfma(const unsigned short* __restrict__ xcb,
                                                     const unsigned short* __restrict__ yqb,
                                                     const float* __restrict__ s_q,
                                                     float* __restrict__ scores,
                                                     unsigned short* __restrict__ s1) {
    int b = blockIdx.y, c0 = blockIdx.x * 64;
    int w = threadIdx.x >> 6, lane = threadIdx.x & 63;
    int lrow = lane & 15, kg = lane >> 4;
    const unsigned short* Ab = xcb + ((size_t)(b * Cn + c0 + w * 16 + lrow)) * En + kg * 8;
    const unsigned short* Bb = yqb + ((size_t)(b * Qn + lrow)) * En + kg * 8;
    f32x4 acc[8] = {};
#pragma unroll
    for (int kc = 0; kc < 7; ++kc) {   // K=200: 6 full chunks + tail (kg==0 only)
        bool valid = (kc < 6) || (kg == 0);
        bf16x8 af = bf16x8{0,0,0,0,0,0,0,0};
        if (valid) af = *(const bf16x8*)(Ab + kc * 32);
#pragma unroll
        for (int j = 0; j < 8; ++j) {
            bf16x8 bfr = bf16x8{0,0,0,0,0,0,0,0};
            if (valid) bfr = *(const bf16x8*)(Bb + (size_t)j * 16 * En + kc * 32);
            acc[j] = __builtin_amdgcn_mfma_f32_16x16x32_bf16(af, bfr, acc[j], 0, 0, 0);
        }
    }
#pragma unroll
    for (int j = 0; j < 8; ++j) {
        float sq = s_q[b * Qn + j * 16 + lrow];
#pragma unroll
        for (int r = 0; r < 4; ++r) acc[j][r] += sq;
    }
    size_t rowbase = (size_t)(b * Cn + c0 + w * 16 + kg * 4);
#pragma unroll
    for (int r = 0; r < 4; ++r)
#pragma unroll
        for (int j = 0; j < 8; ++j)
            scores[(rowbase + r) * Qn + j * 16 + lrow] = acc[j][r];
    // row softmax: row lives in 16 lanes (same kg), 8 regs each
#pragma unroll
    for (int r = 0; r < 4; ++r) {
        float m = acc[0][r];
#pragma unroll
        for (int j = 1; j < 8; ++j) m = fmaxf(m, acc[j][r]);
        for (int d = 1; d < 16; d <<= 1) m = fmaxf(m, __shfl_xor(m, d, 64));
        float ssum = 0.f;
#pragma unroll
        for (int j = 0; j < 8; ++j) {
            float e_ = __expf(acc[j][r] - m);
            acc[j][r] = e_;
            ssum += e_;
        }
        for (int d = 1; d < 16; d <<= 1) ssum += __shfl_xor(ssum, d, 64);
        float si = 1.f / ssum;
#pragma unroll
        for (int j = 0; j < 8; ++j)
            s1[(rowbase + r) * Qn + j * 16 + lrow] = f2bf(acc[j][r] * si);
    }
}

// ---- k_colpart / k_colcomb ------------------------------------------------
__global__ void k_colpart(const float* __restrict__ scores,
                          float* __restrict__ cpM, float* __restrict__ cpS) {
    int b = blockIdx.y, cch = blockIdx.x;
    int q = threadIdx.x;
    const float* base = scores + (size_t)(b * Cn + cch * 128) * Qn + q;
    float m = -1e30f, s = 0.f;
    for (int c = 0; c < 128; c++) {
        float x = base[(size_t)c * Qn];
        float nm = fmaxf(m, x);
        s = s * __expf(m - nm) + __expf(x - nm);
        m = nm;
    }
    cpM[(b * 16 + cch) * 128 + q] = m;
    cpS[(b * 16 + cch) * 128 + q] = s;
}

__global__ void k_colcomb(const float* __restrict__ cpM, const float* __restrict__ cpS,
                          float* __restrict__ colM, float* __restrict__ colSi) {
    int b = blockIdx.x, q = threadIdx.x;
    float m = -1e30f;
    for (int k = 0; k < 16; k++) m = fmaxf(m, cpM[(b * 16 + k) * 128 + q]);
    float s = 0.f;
    for (int k = 0; k < 16; k++) s += cpS[(b * 16 + k) * 128 + q] * __expf(cpM[(b * 16 + k) * 128 + q] - m);
    colM[b * 128 + q] = m;
    colSi[b * 128 + q] = 1.f / s;
}

// ---- k_s2t: s2T[b][q][c] = bf16(exp(scores[c][q]-colM[q])*colSi[q]) -------
__global__ __launch_bounds__(256) void k_s2t(const float* __restrict__ scores,
                                             const float* __restrict__ colM,
                                             const float* __restrict__ colSi,
                                             unsigned short* __restrict__ s2T) {
    int ct = blockIdx.x, qt = blockIdx.y, b = blockIdx.z;
    int c0 = ct * 64, q0 = qt * 64;
    int tid = threadIdx.x;
    __shared__ float t[64][65];
    for (int i = tid; i < 64 * 64; i += 256) {
        int ci = i >> 6, qi = i & 63;
        t[ci][qi] = scores[((size_t)(b * Cn + c0 + ci)) * Qn + q0 + qi];
    }
    __syncthreads();
    for (int i = tid; i < 64 * 64; i += 256) {
        int qi = i >> 6, ci = i & 63;
        int q = q0 + qi;
        float v = __expf(t[ci][qi] - colM[b * Qn + q]) * colSi[b * Qn + q];
        s2T[((size_t)(b * Qn + q)) * Cn + c0 + ci] = f2bf(v);
    }
}

// ---- k_xcT: xcT[b][e][c] bf16 (rows 200..207 zero) ------------------------
__global__ __launch_bounds__(256) void k_xcT(const float* __restrict__ xc,
                                             unsigned short* __restrict__ xcT) {
    int ct = blockIdx.x, et = blockIdx.y, b = blockIdx.z;
    int c0 = ct * 64, e0 = et * 64;
    int tid = threadIdx.x;
    __shared__ float t[64][65];
    for (int i = tid; i < 64 * 64; i += 256) {
        int ci = i >> 6, ei = i & 63;
        int e = e0 + ei;
        t[ci][ei] = (e < En) ? xc[((size_t)(b * Cn + c0 + ci)) * En + e] : 0.f;
    }
    __syncthreads();
    for (int i = tid; i < 64 * 64; i += 256) {
        int ei = i >> 6, ci = i & 63;
        int e = e0 + ei;
        if (e < EP)
            xcT[((size_t)(b * EP + e)) * Cn + c0 + ci] = f2bf(t[ci][ei]);
    }
}

// ---- k_xqT: xqaT rows [0,200) = xq^T bf16 ---------------------------------
__global__ __launch_bounds__(256) void k_xqT(const float* __restrict__ xq,
                                             unsigned short* __restrict__ xqaT) {
    int et = blockIdx.x, qt = blockIdx.y, b = blockIdx.z;
    int e0 = et * 64, q0 = qt * 64;
    int tid = threadIdx.x;
    __shared__ float t[64][65];
    for (int i = tid; i < 64 * 64; i += 256) {
        int qi = i >> 6, ei = i & 63;
        int e = e0 + ei;
        t[qi][ei] = (e < En) ? xq[((size_t)(b * Qn + q0 + qi)) * En + e] : 0.f;
    }
    __syncthreads();
    for (int i = tid; i < 64 * 64; i += 256) {
        int ei = i >> 6, qi = i & 63;
        int e = e0 + ei;
        if (e < En)
            xqaT[((size_t)(b * 400 + e)) * Qn + q0 + qi] = f2bf(t[qi][ei]);
    }
}

// ---- k_a_mfma: a^T[e][q] = sum_c xcT[e][c]*s2T[q][c]; write xqaT[200+e][q]
// grid (13 etiles, 16 b), 4 waves; wave w: n-cols q = w*16..+16 and 64+w*16..+16
__global__ __launch_bounds__(256) void k_a_mfma(const unsigned short* __restrict__ s2T,
                                                const unsigned short* __restrict__ xcT,
                                                unsigned short* __restrict__ xqaT) {
    int mt = blockIdx.x, b = blockIdx.y;
    int w = threadIdx.x >> 6, lane = threadIdx.x & 63;
    int lrow = lane & 15, kg = lane >> 4;
    const unsigned short* Ab = xcT + ((size_t)(b * EP + mt * 16 + lrow)) * Cn + kg * 8;
    const unsigned short* B0 = s2T + ((size_t)(b * Qn + w * 16 + lrow)) * Cn + kg * 8;
    const unsigned short* B1 = B0 + (size_t)64 * Cn;
    f32x4 acc0 = {}, acc1 = {};
#pragma unroll 4
    for (int kc = 0; kc < 64; ++kc) {
        bf16x8 af = *(const bf16x8*)(Ab + kc * 32);
        bf16x8 b0 = *(const bf16x8*)(B0 + kc * 32);
        bf16x8 b1 = *(const bf16x8*)(B1 + kc * 32);
        acc0 = __builtin_amdgcn_mfma_f32_16x16x32_bf16(af, b0, acc0, 0, 0, 0);
        acc1 = __builtin_amdgcn_mfma_f32_16x16x32_bf16(af, b1, acc1, 0, 0, 0);
    }
#pragma unroll
    for (int r = 0; r < 4; ++r) {
        int e = mt * 16 + kg * 4 + r;
        if (e < En) {
            xqaT[((size_t)(b * 400 + 200 + e)) * Qn + w * 16 + lrow] = f2bf(acc0[r]);
            xqaT[((size_t)(b * 400 + 200 + e)) * Qn + 64 + w * 16 + lrow] = f2bf(acc1[r]);
        }
    }
}

// ---- k_cq: [c2q|q2c] = S1 @ xqaT^T ----------------------------------------
__global__ __launch_bounds__(256) void k_cq(const unsigned short* __restrict__ s1,
                                            const unsigned short* __restrict__ xqaT,
                                            unsigned short* __restrict__ cq) {
    int b = blockIdx.z;
    int c0 = blockIdx.x * 64;
    int n0 = blockIdx.y * 80;
    int w = threadIdx.x >> 6, lane = threadIdx.x & 63;
    int lrow = lane & 15, kg = lane >> 4;
    const unsigned short* Abase = s1 + ((size_t)(b * Cn + c0 + w * 16 + lrow)) * 128 + kg * 8;
    const unsigned short* Bbase = xqaT + ((size_t)(b * 400 + n0 + lrow)) * 128 + kg * 8;
    f32x4 acc[5] = {};
#pragma unroll
    for (int kc = 0; kc < 4; ++kc) {
        bf16x8 af = *(const bf16x8*)(Abase + kc * 32);
#pragma unroll
        for (int j = 0; j < 5; ++j) {
            bf16x8 bfr = *(const bf16x8*)(Bbase + (size_t)j * 16 * 128 + kc * 32);
            acc[j] = __builtin_amdgcn_mfma_f32_16x16x32_bf16(af, bfr, acc[j], 0, 0, 0);
        }
    }
    int drow = c0 + w * 16 + kg * 4;
#pragma unroll
    for (int j = 0; j < 5; ++j)
#pragma unroll
        for (int r = 0; r < 4; ++r)
            cq[((size_t)(b * Cn + drow + r)) * 400 + n0 + j * 16 + lrow] = f2bf(acc[j][r]);
}

// ---- k_out: feats (32 rows, LDS bf16) + MFMA projection -------------------
__global__ __launch_bounds__(256) void k_out(const float* __restrict__ xc,
                                             const unsigned short* __restrict__ cq,
                                             const unsigned short* __restrict__ wpb,
                                             const float* __restrict__ bp,
                                             float* __restrict__ out) {
    int b = blockIdx.y;
    int c0 = blockIdx.x * 32;
    int tid = threadIdx.x;
    __shared__ unsigned short feats[32 * 808];
    const float* xcb_ = xc + ((size_t)(b * Cn + c0)) * En;
    const unsigned short* cqb = cq + ((size_t)(b * Cn + c0)) * 400;
    for (int i = tid; i < 32 * En; i += 256) {
        int c = i / En, e = i - c * En;
        float x = xcb_[c * En + e];
        unsigned short c2b = cqb[c * 400 + e];
        float c2 = bf2f(c2b);
        float q2 = bf2f(cqb[c * 400 + 200 + e]);
        int base = c * 808;
        feats[base + e] = f2bf(x);
        feats[base + 200 + e] = c2b;
        feats[base + 400 + e] = f2bf(x * c2);
        feats[base + 600 + e] = f2bf(x * q2);
    }
    __syncthreads();
    int w = tid >> 6, lane = tid & 63;
    int lrow = lane & 15, kg = lane >> 4;
    int mt = w & 1, nh = w >> 1;
    f32x4 acc[4] = {};
    const unsigned short* Af = feats + (mt * 16 + lrow) * 808 + kg * 8;
    const unsigned short* Bb = wpb + ((size_t)(nh * 64 + lrow)) * Fn + kg * 8;
#pragma unroll 5
    for (int kc = 0; kc < 25; ++kc) {
        bf16x8 af = *(const bf16x8*)(Af + kc * 32);
#pragma unroll
        for (int j = 0; j < 4; ++j) {
            bf16x8 bfr = *(const bf16x8*)(Bb + (size_t)j * 16 * Fn + kc * 32);
            acc[j] = __builtin_amdgcn_mfma_f32_16x16x32_bf16(af, bfr, acc[j], 0, 0, 0);
        }
    }
    int row0 = c0 + mt * 16 + kg * 4;
#pragma unroll
    for (int j = 0; j < 4; ++j) {
        int col = nh * 64 + j * 16 + lrow;
        float bpv = bp[col];
#pragma unroll
        for (int r = 0; r < 4; ++r)
            out[((size_t)(b * Cn + row0 + r)) * On + col] = acc[j][r] + bpv;
    }
}

extern "C" void kernel_launch(void* const* d_in, const int* in_sizes, int n_in,
                              void* d_out, int out_size, void* d_ws, size_t ws_size,
                              hipStream_t stream) {
    const float* xc = (const float*)d_in[0];
    const float* xq = (const float*)d_in[1];
    const float* wsim = (const float*)d_in[2];
    const float* wp = (const float*)d_in[3];
    const float* bp = (const float*)d_in[4];
    float* out = (float*)d_out;
    float* ws = (float*)d_ws;

    // region 0: scores fp32 (dead after k_s2t); cq_bf aliases it (k_cq..k_out)
    float* scores = ws;                                            // 4,194,304 f
    unsigned short* cq_bf = (unsigned short*)ws;                   // 6,553,600 bf16
    // region 1: xc_bf (dead after k_scores_mfma); xcT_bf aliases it
    unsigned short* xc_bf  = (unsigned short*)(ws + 4194304);      // 6,553,600 bf16
    unsigned short* xcT_bf = (unsigned short*)(ws + 4194304);      // 6,815,744 bf16 (region 3,407,872 f)
    unsigned short* s1_bf  = (unsigned short*)(ws + 7602176);      // 4,194,304 bf16
    unsigned short* s2T_bf = (unsigned short*)(ws + 9699328);      // 4,194,304 bf16
    unsigned short* yq_bf  = (unsigned short*)(ws + 11796480);     //   409,600 bf16
    float* s_q    = ws + 12001280;   //  2,048 f
    float* cpM    = ws + 12003328;   // 32,768 f
    float* cpS    = ws + 12036096;   // 32,768 f
    float* colM   = ws + 12068864;   //  2,048 f
    float* colSi  = ws + 12070912;   //  2,048 f
    unsigned short* xqaT_bf = (unsigned short*)(ws + 12072960);    //   819,200 bf16
    unsigned short* wp_bf   = (unsigned short*)(ws + 12482560);    //   102,400 bf16
    // total: 12,533,760 floats = 50.1 MB

    k_yq<<<512, 256, 0, stream>>>(xq, wsim, yq_bf, s_q);
    k_cast_xc<<<6400, 256, 0, stream>>>(xc, xc_bf);
    k_prep_wp<<<100, 256, 0, stream>>>(wp, wp_bf);
    k_scores_mfma<<<dim3(32, 16), 256, 0, stream>>>(xc_bf, yq_bf, s_q, scores, s1_bf);
    k_colpart<<<dim3(16, 16), 128, 0, stream>>>(scores, cpM, cpS);
    k_colcomb<<<16, 128, 0, stream>>>(cpM, cpS, colM, colSi);
    k_s2t<<<dim3(32, 2, 16), 256, 0, stream>>>(scores, colM, colSi, s2T_bf);
    k_xcT<<<dim3(32, 4, 16), 256, 0, stream>>>(xc, xcT_bf);      // xc_bf dead; alias ok
    k_xqT<<<dim3(4, 2, 16), 256, 0, stream>>>(xq, xqaT_bf);
    k_a_mfma<<<dim3(13, 16), 256, 0, stream>>>(s2T_bf, xcT_bf, xqaT_bf);
    // scores dead from here; cq_bf aliases region 0
    k_cq<<<dim3(32, 5, 16), 256, 0, stream>>>(s1_bf, xqaT_bf, cq_bf);
    k_out<<<dim3(64, 16), 256, 0, stream>>>(xc, cq_bf, wp_bf, bp, out);
}